// Round 1
// baseline (1770.188 us; speedup 1.0000x reference)
//
#include <hip/hip_runtime.h>

// Problem constants (from reference)
static constexpr int SEQ  = 20;
static constexpr int FEAT = 5;
static constexpr int NU1  = 10;
static constexpr int NU2  = 7;
static constexpr int NU3  = 4;
static constexpr int NOUT = 4;

// Fast HW transcendentals: v_exp_f32 computes 2^x, v_rcp_f32 ~1ulp recip.
// Accuracy ~1e-7 rel, far inside the 1.46e-2 harness threshold.
__device__ __forceinline__ float hexp2(float x) { return __builtin_amdgcn_exp2f(x); }
__device__ __forceinline__ float hrcp(float x)  { return __builtin_amdgcn_rcpf(x); }

// sigmoid(x) = 1/(1+e^-x) = 1/(1+2^(-x*log2e))
__device__ __forceinline__ float sigm(float x) {
    return hrcp(1.0f + hexp2(x * -1.4426950408889634f));
}
// tanh(x) = 1 - 2/(1+e^(2x)) = 1 - 2/(1+2^(x*2*log2e))
// x->+inf: exp->inf, rcp->0, result->1.  x->-inf: exp->0, result->-1.  Correct limits.
__device__ __forceinline__ float ftanh(float x) {
    return 1.0f - 2.0f * hrcp(1.0f + hexp2(x * 2.8853900817779268f));
}

// One LSTM timestep, Keras gate order [i, f, g, o], all weights wave-uniform
// (constant indices after unroll -> s_load from K$, co-issued on scalar pipe).
template <int IN, int U>
__device__ __forceinline__ void lstm_step(const float* __restrict__ Wk,
                                          const float* __restrict__ Wr,
                                          const float* __restrict__ b,
                                          const float (&xin)[IN],
                                          float (&h)[U], float (&c)[U]) {
    float hn[U];
#pragma unroll
    for (int u = 0; u < U; ++u) {
        float zi = b[u];
        float zf = b[U + u];
        float zg = b[2 * U + u];
        float zo = b[3 * U + u];
#pragma unroll
        for (int f = 0; f < IN; ++f) {
            const float xf = xin[f];
            zi = fmaf(xf, Wk[f * 4 * U + 0 * U + u], zi);
            zf = fmaf(xf, Wk[f * 4 * U + 1 * U + u], zf);
            zg = fmaf(xf, Wk[f * 4 * U + 2 * U + u], zg);
            zo = fmaf(xf, Wk[f * 4 * U + 3 * U + u], zo);
        }
#pragma unroll
        for (int k = 0; k < U; ++k) {
            const float hk = h[k];
            zi = fmaf(hk, Wr[k * 4 * U + 0 * U + u], zi);
            zf = fmaf(hk, Wr[k * 4 * U + 1 * U + u], zf);
            zg = fmaf(hk, Wr[k * 4 * U + 2 * U + u], zg);
            zo = fmaf(hk, Wr[k * 4 * U + 3 * U + u], zo);
        }
        const float gi = sigm(zi);
        const float gf = sigm(zf);
        const float gg = ftanh(zg);
        const float go = sigm(zo);
        const float cn = gf * c[u] + gi * gg;
        c[u] = cn;
        hn[u] = go * ftanh(cn);
    }
#pragma unroll
    for (int u = 0; u < U; ++u) h[u] = hn[u];
}

// One thread per batch element; all 3 LSTM layers + dense fused in registers.
__global__ __launch_bounds__(256) void lstm3_fused(
    const float* __restrict__ x,
    const float* __restrict__ Wk1, const float* __restrict__ Wr1, const float* __restrict__ b1,
    const float* __restrict__ Wk2, const float* __restrict__ Wr2, const float* __restrict__ b2,
    const float* __restrict__ Wk3, const float* __restrict__ Wr3, const float* __restrict__ b3,
    const float* __restrict__ Wd, const float* __restrict__ bd,
    float* __restrict__ out, int B) {
    const int bidx = blockIdx.x * blockDim.x + threadIdx.x;
    if (bidx >= B) return;

    const float* __restrict__ xb = x + (size_t)bidx * (SEQ * FEAT);
    float4* __restrict__ outb = (float4*)(out + (size_t)bidx * (SEQ * NOUT));

    float h1[NU1], c1[NU1], h2[NU2], c2[NU2], h3[NU3], c3[NU3];
#pragma unroll
    for (int u = 0; u < NU1; ++u) { h1[u] = 0.f; c1[u] = 0.f; }
#pragma unroll
    for (int u = 0; u < NU2; ++u) { h2[u] = 0.f; c2[u] = 0.f; }
#pragma unroll
    for (int u = 0; u < NU3; ++u) { h3[u] = 0.f; c3[u] = 0.f; }

    for (int t = 0; t < SEQ; ++t) {
        float xv[FEAT];
#pragma unroll
        for (int f = 0; f < FEAT; ++f) xv[f] = xb[t * FEAT + f];

        lstm_step<FEAT, NU1>(Wk1, Wr1, b1, xv, h1, c1);
        lstm_step<NU1, NU2>(Wk2, Wr2, b2, h1, h2, c2);
        lstm_step<NU2, NU3>(Wk3, Wr3, b3, h2, h3, c3);

        // dense + sigmoid, 16B-aligned float4 store (b*320 + t*16 bytes)
        float od[NOUT];
#pragma unroll
        for (int o = 0; o < NOUT; ++o) {
            float z = bd[o];
#pragma unroll
            for (int u = 0; u < NU3; ++u) z = fmaf(h3[u], Wd[u * NOUT + o], z);
            od[o] = sigm(z);
        }
        outb[t] = make_float4(od[0], od[1], od[2], od[3]);
    }
}

extern "C" void kernel_launch(void* const* d_in, const int* in_sizes, int n_in,
                              void* d_out, int out_size, void* d_ws, size_t ws_size,
                              hipStream_t stream) {
    const float* x   = (const float*)d_in[0];
    const float* Wk1 = (const float*)d_in[1];
    const float* Wr1 = (const float*)d_in[2];
    const float* b1  = (const float*)d_in[3];
    const float* Wk2 = (const float*)d_in[4];
    const float* Wr2 = (const float*)d_in[5];
    const float* b2  = (const float*)d_in[6];
    const float* Wk3 = (const float*)d_in[7];
    const float* Wr3 = (const float*)d_in[8];
    const float* b3  = (const float*)d_in[9];
    const float* Wd  = (const float*)d_in[10];
    const float* bd  = (const float*)d_in[11];
    float* out = (float*)d_out;

    const int B = in_sizes[0] / (SEQ * FEAT);
    const int block = 256;
    const int grid = (B + block - 1) / block;
    lstm3_fused<<<grid, block, 0, stream>>>(x, Wk1, Wr1, b1, Wk2, Wr2, b2,
                                            Wk3, Wr3, b3, Wd, bd, out, B);
}

// Round 2
// 634.378 us; speedup vs baseline: 2.7904x; 2.7904x over previous
//
#include <hip/hip_runtime.h>

// Problem constants (from reference)
static constexpr int SEQ  = 20;
static constexpr int FEAT = 5;
static constexpr int NU1  = 10;
static constexpr int NU2  = 7;
static constexpr int NU3  = 4;
static constexpr int NOUT = 4;
static constexpr int R    = 2;   // batch elements per thread (register blocking)

// Fast HW transcendentals: v_exp_f32 computes 2^x, v_rcp_f32 ~1ulp recip.
__device__ __forceinline__ float hexp2(float x) { return __builtin_amdgcn_exp2f(x); }
__device__ __forceinline__ float hrcp(float x)  { return __builtin_amdgcn_rcpf(x); }

// sigmoid(x) = 1/(1+2^(-x*log2e))
__device__ __forceinline__ float sigm(float x) {
    return hrcp(1.0f + hexp2(x * -1.4426950408889634f));
}
// tanh(x) = 1 - 2/(1+2^(x*2*log2e)); correct +/-1 limits.
__device__ __forceinline__ float ftanh(float x) {
    return 1.0f - 2.0f * hrcp(1.0f + hexp2(x * 2.8853900817779268f));
}

// One LSTM timestep for R batch elements. Weights are wave-uniform: each
// weight is loaded once (s_load) and feeds R independent FMAs — register
// blocking amortizes the scalar-load stream that round-1 counters implicate.
template <int IN, int U>
__device__ __forceinline__ void lstm_step(const float* __restrict__ Wk,
                                          const float* __restrict__ Wr,
                                          const float* __restrict__ b,
                                          const float (&xin)[R][IN],
                                          float (&h)[R][U], float (&c)[R][U]) {
    float hn[R][U];
#pragma unroll
    for (int u = 0; u < U; ++u) {
        float zi[R], zf[R], zg[R], zo[R];
#pragma unroll
        for (int r = 0; r < R; ++r) {
            zi[r] = b[u];
            zf[r] = b[U + u];
            zg[r] = b[2 * U + u];
            zo[r] = b[3 * U + u];
        }
#pragma unroll
        for (int f = 0; f < IN; ++f) {
            const float wi = Wk[f * 4 * U + 0 * U + u];
            const float wf = Wk[f * 4 * U + 1 * U + u];
            const float wg = Wk[f * 4 * U + 2 * U + u];
            const float wo = Wk[f * 4 * U + 3 * U + u];
#pragma unroll
            for (int r = 0; r < R; ++r) {
                const float xf = xin[r][f];
                zi[r] = fmaf(xf, wi, zi[r]);
                zf[r] = fmaf(xf, wf, zf[r]);
                zg[r] = fmaf(xf, wg, zg[r]);
                zo[r] = fmaf(xf, wo, zo[r]);
            }
        }
#pragma unroll
        for (int k = 0; k < U; ++k) {
            const float wi = Wr[k * 4 * U + 0 * U + u];
            const float wf = Wr[k * 4 * U + 1 * U + u];
            const float wg = Wr[k * 4 * U + 2 * U + u];
            const float wo = Wr[k * 4 * U + 3 * U + u];
#pragma unroll
            for (int r = 0; r < R; ++r) {
                const float hk = h[r][k];
                zi[r] = fmaf(hk, wi, zi[r]);
                zf[r] = fmaf(hk, wf, zf[r]);
                zg[r] = fmaf(hk, wg, zg[r]);
                zo[r] = fmaf(hk, wo, zo[r]);
            }
        }
#pragma unroll
        for (int r = 0; r < R; ++r) {
            const float gi = sigm(zi[r]);
            const float gf = sigm(zf[r]);
            const float gg = ftanh(zg[r]);
            const float go = sigm(zo[r]);
            const float cn = gf * c[r][u] + gi * gg;
            c[r][u] = cn;
            hn[r][u] = go * ftanh(cn);
        }
    }
#pragma unroll
    for (int r = 0; r < R; ++r)
#pragma unroll
        for (int u = 0; u < U; ++u) h[r][u] = hn[r][u];
}

__global__ __launch_bounds__(256) void lstm3_fused(
    const float* __restrict__ x,
    const float* __restrict__ Wk1, const float* __restrict__ Wr1, const float* __restrict__ b1,
    const float* __restrict__ Wk2, const float* __restrict__ Wr2, const float* __restrict__ b2,
    const float* __restrict__ Wk3, const float* __restrict__ Wr3, const float* __restrict__ b3,
    const float* __restrict__ Wd, const float* __restrict__ bd,
    float* __restrict__ out, int B) {
    const int tid = blockIdx.x * blockDim.x + threadIdx.x;
    const int Bsub = B / R;             // each thread: elems tid, tid+Bsub, ...
    if (tid >= Bsub) return;

    const float* __restrict__ xb[R];
    float4* __restrict__ outb[R];
#pragma unroll
    for (int r = 0; r < R; ++r) {
        const int e = tid + r * Bsub;
        xb[r]   = x + (size_t)e * (SEQ * FEAT);
        outb[r] = (float4*)(out + (size_t)e * (SEQ * NOUT));
    }

    float h1[R][NU1], c1[R][NU1], h2[R][NU2], c2[R][NU2], h3[R][NU3], c3[R][NU3];
#pragma unroll
    for (int r = 0; r < R; ++r) {
#pragma unroll
        for (int u = 0; u < NU1; ++u) { h1[r][u] = 0.f; c1[r][u] = 0.f; }
#pragma unroll
        for (int u = 0; u < NU2; ++u) { h2[r][u] = 0.f; c2[r][u] = 0.f; }
#pragma unroll
        for (int u = 0; u < NU3; ++u) { h3[r][u] = 0.f; c3[r][u] = 0.f; }
    }

    // Keep the body I$-resident: do NOT let the compiler unroll 20x.
#pragma unroll 1
    for (int t = 0; t < SEQ; ++t) {
        float xv[R][FEAT];
#pragma unroll
        for (int r = 0; r < R; ++r)
#pragma unroll
            for (int f = 0; f < FEAT; ++f) xv[r][f] = xb[r][t * FEAT + f];

        lstm_step<FEAT, NU1>(Wk1, Wr1, b1, xv, h1, c1);
        lstm_step<NU1, NU2>(Wk2, Wr2, b2, h1, h2, c2);
        lstm_step<NU2, NU3>(Wk3, Wr3, b3, h2, h3, c3);

        // dense + sigmoid, 16B-aligned float4 store per element
#pragma unroll
        for (int r = 0; r < R; ++r) {
            float od[NOUT];
#pragma unroll
            for (int o = 0; o < NOUT; ++o) {
                float z = bd[o];
#pragma unroll
                for (int u = 0; u < NU3; ++u) z = fmaf(h3[r][u], Wd[u * NOUT + o], z);
                od[o] = sigm(z);
            }
            outb[r][t] = make_float4(od[0], od[1], od[2], od[3]);
        }
    }
}

extern "C" void kernel_launch(void* const* d_in, const int* in_sizes, int n_in,
                              void* d_out, int out_size, void* d_ws, size_t ws_size,
                              hipStream_t stream) {
    const float* x   = (const float*)d_in[0];
    const float* Wk1 = (const float*)d_in[1];
    const float* Wr1 = (const float*)d_in[2];
    const float* b1  = (const float*)d_in[3];
    const float* Wk2 = (const float*)d_in[4];
    const float* Wr2 = (const float*)d_in[5];
    const float* b2  = (const float*)d_in[6];
    const float* Wk3 = (const float*)d_in[7];
    const float* Wr3 = (const float*)d_in[8];
    const float* b3  = (const float*)d_in[9];
    const float* Wd  = (const float*)d_in[10];
    const float* bd  = (const float*)d_in[11];
    float* out = (float*)d_out;

    const int B = in_sizes[0] / (SEQ * FEAT);
    const int threads = B / R;
    const int block = 256;
    const int grid = (threads + block - 1) / block;
    lstm3_fused<<<grid, block, 0, stream>>>(x, Wk1, Wr1, b1, Wk2, Wr2, b2,
                                            Wk3, Wr3, b3, Wd, bd, out, B);
}